// Round 1
// baseline (923.033 us; speedup 1.0000x reference)
//
#include <hip/hip_runtime.h>

#define BB 32
#define SS 1024
#define CINN 16

// ---------- accurate-for-tiny-arguments activations ----------
__device__ __forceinline__ float tanh_fast(float x) {
    float x2 = x * x;
    // |x|<=0.25: odd series, relative err < 4e-7
    float p = x * (1.f + x2 * (-0.33333334f + x2 * (0.13333333f - x2 * 0.05396825f)));
    float e = __expf(2.f * x);
    float q = 1.f - 2.f * __builtin_amdgcn_rcpf(1.f + e);
    return (fabsf(x) > 0.25f) ? q : p;
}
__device__ __forceinline__ float sig_fast(float x) {
    return 0.5f + 0.5f * tanh_fast(0.5f * x);
}

// ---------- kernel 1: fused 3x dsconv + U_i projection -> ri (B,S,16) ----------
__global__ __launch_bounds__(256) void conv_ri_kernel(
    const float* __restrict__ x,
    const float* __restrict__ w1d, const float* __restrict__ b1d,
    const float* __restrict__ w1p, const float* __restrict__ b1p,
    const float* __restrict__ w2d, const float* __restrict__ b2d,
    const float* __restrict__ w2p, const float* __restrict__ b2p,
    const float* __restrict__ w3d, const float* __restrict__ b3d,
    const float* __restrict__ w3p, const float* __restrict__ b3p,
    const float* __restrict__ Ui,
    float* __restrict__ ri)
{
    const int b = blockIdx.x >> 4;
    const int tile = blockIdx.x & 15;
    const int base = tile * 64;
    const int t = threadIdx.x;

    __shared__ float lds[12576];
    float* xs  = lds;          // [70][16]  @0
    float* y1s = lds + 1120;   // [68][16]
    float* z1s = lds + 2208;   // [68][32]
    float* y2s = lds;          // [66][32]  (overlays xs/y1s, dead)
    float* z2s = lds + 4384;   // [66][64]
    float* y3s = lds;          // [64][64]  (overlays y2s, dead)
    float* z3s = lds + 4384;   // [64][128] (overlays z2s, dead)

    // P0: load x tile with halo 3, zero-padded
    for (int idx = t; idx < 70 * 16; idx += 256) {
        int p = idx >> 4, c = idx & 15;
        int s = base - 3 + p;
        xs[idx] = (s >= 0 && s < SS) ? x[((size_t)b * SS + s) * CINN + c] : 0.f;
    }
    __syncthreads();
    // P1: y1 (dw1) at pos base-2+p, p<68
    for (int idx = t; idx < 68 * 16; idx += 256) {
        int p = idx >> 4, c = idx & 15;
        float acc = b1d[c];
#pragma unroll
        for (int k = 0; k < 3; ++k) acc += xs[(p + k) * 16 + c] * w1d[c * 3 + k];
        y1s[idx] = acc;
    }
    __syncthreads();
    // P2: z1 (pw1), zeroed at OOB positions (padding for next stage)
    for (int idx = t; idx < 68 * 32; idx += 256) {
        int p = idx >> 5, o = idx & 31;
        int pos = base - 2 + p;
        float acc = b1p[o];
#pragma unroll
        for (int c = 0; c < 16; ++c) acc += y1s[p * 16 + c] * w1p[o * 16 + c];
        z1s[idx] = (pos >= 0 && pos < SS) ? acc : 0.f;
    }
    __syncthreads();
    // P3: y2 (dw2) at pos base-1+p, p<66
    for (int idx = t; idx < 66 * 32; idx += 256) {
        int p = idx >> 5, c = idx & 31;
        float acc = b2d[c];
#pragma unroll
        for (int k = 0; k < 3; ++k) acc += z1s[(p + k) * 32 + c] * w2d[c * 3 + k];
        y2s[idx] = acc;
    }
    __syncthreads();
    // P4: z2 (pw2), zeroed OOB
    for (int idx = t; idx < 66 * 64; idx += 256) {
        int p = idx >> 6, o = idx & 63;
        int pos = base - 1 + p;
        float acc = b2p[o];
        for (int c = 0; c < 32; ++c) acc += y2s[p * 32 + c] * w2p[o * 32 + c];
        z2s[idx] = (pos >= 0 && pos < SS) ? acc : 0.f;
    }
    __syncthreads();
    // P5: y3 (dw3) at pos base+p, p<64
    for (int idx = t; idx < 64 * 64; idx += 256) {
        int p = idx >> 6, c = idx & 63;
        float acc = b3d[c];
#pragma unroll
        for (int k = 0; k < 3; ++k) acc += z2s[(p + k) * 64 + c] * w3d[c * 3 + k];
        y3s[idx] = acc;
    }
    __syncthreads();
    // P6: z3 (pw3)
    for (int idx = t; idx < 64 * 128; idx += 256) {
        int p = idx >> 7, o = idx & 127;
        float acc = b3p[o];
        for (int c = 0; c < 64; ++c) acc += y3s[p * 64 + c] * w3p[o * 64 + c];
        z3s[idx] = acc;
    }
    __syncthreads();
    // P7: ri = z3 @ U_i  (64 x 16)
    for (int idx = t; idx < 64 * 16; idx += 256) {
        int p = idx >> 4, j = idx & 15;
        float acc = 0.f;
        for (int o = 0; o < 128; ++o) acc += z3s[p * 128 + o] * Ui[o * 16 + j];
        ri[((size_t)b * SS + base + p) * 16 + j] = acc;
    }
}

// ---------- kernel 2: low-rank LSTM scan, 1 block/batch, 128 threads ----------
__global__ __launch_bounds__(128, 1) void lstm_scan_kernel(
    const float* __restrict__ ri,
    const float* __restrict__ Uh,
    const float* __restrict__ Vi,
    const float* __restrict__ Vh,
    const float* __restrict__ bias_i,
    const float* __restrict__ bias_h,
    float* __restrict__ hs)
{
    const int b = blockIdx.x;
    const int t = threadIdx.x;           // owns cell element e = t
    const int j16 = t & 15, grp = t >> 4, w = t >> 6;

    extern __shared__ float smem[];
    float* rlds = smem;                  // [1024][16] input-side low-rank
    float* hch  = smem + 16384;          // [16][128] h ring buffer
    float* rws  = smem + 16384 + 2048;   // [2][16] per-wave partial r

    float Uv[16];
#pragma unroll
    for (int i = 0; i < 16; ++i) Uv[i] = Uh[(grp * 16 + i) * 16 + j16];

    float VIv[4][16], VHv[4][16], bsum[4];
#pragma unroll
    for (int k = 0; k < 4; ++k) {
#pragma unroll
        for (int j = 0; j < 16; ++j) {
            VIv[k][j] = Vi[j * 512 + k * 128 + t];
            VHv[k][j] = Vh[j * 512 + k * 128 + t];
        }
        bsum[k] = bias_i[k * 128 + t] + bias_h[k * 128 + t];
    }

    { // preload all ri rows for this batch (64 KB) -> no global loads in loop
        const float4* rg = (const float4*)(ri + (size_t)b * (SS * 16));
        float4* r4 = (float4*)rlds;
        for (int i = t; i < 4096; i += 128) r4[i] = rg[i];
    }
    hch[15 * 128 + t] = 0.f;
    float c = 0.f;
    float* hsb = hs + (size_t)b * (SS * 128);
    __syncthreads();

    int prow = 15;
    for (int step = 0; step < SS; ++step) {
        // phase A: partial r_j over this group's 16 h entries
        const float4* hp4 = (const float4*)(hch + prow * 128 + grp * 16);
        float4 h0 = hp4[0], h1 = hp4[1], h2 = hp4[2], h3 = hp4[3];
        float pa = h0.x * Uv[0] + h0.y * Uv[1] + h0.z * Uv[2] + h0.w * Uv[3];
        float pb = h1.x * Uv[4] + h1.y * Uv[5] + h1.z * Uv[6] + h1.w * Uv[7];
        float pc = h2.x * Uv[8] + h2.y * Uv[9] + h2.z * Uv[10] + h2.w * Uv[11];
        float pd = h3.x * Uv[12] + h3.y * Uv[13] + h3.z * Uv[14] + h3.w * Uv[15];
        float partial = (pa + pb) + (pc + pd);
        partial += __shfl_xor(partial, 16, 64);
        partial += __shfl_xor(partial, 32, 64);
        if ((t & 63) < 16) rws[w * 16 + j16] = partial;
        __syncthreads();

        const float4* rwp = (const float4*)rws;
        float4 A0 = rwp[0], A1 = rwp[1], A2 = rwp[2], A3 = rwp[3];
        float4 B0 = rwp[4], B1 = rwp[5], B2 = rwp[6], B3 = rwp[7];
        const float4* rvp = (const float4*)(rlds + step * 16);
        float4 R0 = rvp[0], R1 = rvp[1], R2 = rvp[2], R3 = rvp[3];

        float rh[16] = {A0.x + B0.x, A0.y + B0.y, A0.z + B0.z, A0.w + B0.w,
                        A1.x + B1.x, A1.y + B1.y, A1.z + B1.z, A1.w + B1.w,
                        A2.x + B2.x, A2.y + B2.y, A2.z + B2.z, A2.w + B2.w,
                        A3.x + B3.x, A3.y + B3.y, A3.z + B3.z, A3.w + B3.w};
        float rv[16] = {R0.x, R0.y, R0.z, R0.w, R1.x, R1.y, R1.z, R1.w,
                        R2.x, R2.y, R2.z, R2.w, R3.x, R3.y, R3.z, R3.w};

        float g0 = bsum[0], g1 = bsum[1], g2 = bsum[2], g3 = bsum[3];
#pragma unroll
        for (int j = 0; j < 16; ++j) {
            g0 += rv[j] * VIv[0][j] + rh[j] * VHv[0][j];
            g1 += rv[j] * VIv[1][j] + rh[j] * VHv[1][j];
            g2 += rv[j] * VIv[2][j] + rh[j] * VHv[2][j];
            g3 += rv[j] * VIv[3][j] + rh[j] * VHv[3][j];
        }

        float si = sig_fast(g0);
        float sf = sig_fast(g1);
        float tc = tanh_fast(g2);
        float so = sig_fast(g3);
        c = sf * c + si * tc;
        float hn = so * tanh_fast(c);

        int hrow = (prow + 1) & 15;
        hch[hrow * 128 + t] = hn;
        __syncthreads();
        if (hrow == 15) { // dump 16 finished rows (thread reads only its own column)
            float* dst = hsb + (size_t)(step - 15) * 128 + t;
#pragma unroll
            for (int m = 0; m < 16; ++m) dst[m * 128] = hch[m * 128 + t];
        }
        prow = hrow;
    }
}

// ---------- kernel 3: last-query attention + head, 1 block/batch ----------
__global__ __launch_bounds__(256) void attn_head_kernel(
    const float* __restrict__ hs,
    const float* __restrict__ Wq, const float* __restrict__ bq,
    const float* __restrict__ Wk,
    const float* __restrict__ Wv, const float* __restrict__ bv,
    const float* __restrict__ Wo, const float* __restrict__ bo,
    const float* __restrict__ Wfc, const float* __restrict__ bfc,
    float* __restrict__ out)
{
    const int b = blockIdx.x;
    const int t = threadIdx.x;
    const float* hb = hs + (size_t)b * (SS * 128);

    __shared__ float hlast[128];
    __shared__ float qv[128];
    __shared__ float wqt[2][128];
    __shared__ float sc[2][1024];
    __shared__ float red[8];
    __shared__ float hbarw[2][128];
    __shared__ float att[128];
    __shared__ float yv[128];

    if (t < 128) hlast[t] = hb[(size_t)1023 * 128 + t];
    __syncthreads();
    if (t < 128) {
        float acc = bq[t];
        for (int c = 0; c < 128; ++c) acc += hlast[c] * Wq[c * 128 + t];
        qv[t] = acc;
    }
    __syncthreads();
    { // wqt[h][c] = sum_d Wk[c][64h+d] * q[64h+d]
        int h = t >> 7, c0 = t & 127;
        float acc = 0.f;
        for (int d = 0; d < 64; ++d) acc += Wk[c0 * 128 + h * 64 + d] * qv[h * 64 + d];
        wqt[h][c0] = acc;
    }
    __syncthreads();
    // scores for all 1024 rows, both heads
    for (int rr = 0; rr < 4; ++rr) {
        int row = (rr << 8) + t;
        const float4* hp = (const float4*)(hb + (size_t)row * 128);
        float a0 = 0.f, a1 = 0.f;
#pragma unroll 8
        for (int cq = 0; cq < 32; ++cq) {
            float4 hv = hp[cq];
            int cb = cq * 4;
            a0 += hv.x * wqt[0][cb] + hv.y * wqt[0][cb + 1] + hv.z * wqt[0][cb + 2] + hv.w * wqt[0][cb + 3];
            a1 += hv.x * wqt[1][cb] + hv.y * wqt[1][cb + 1] + hv.z * wqt[1][cb + 2] + hv.w * wqt[1][cb + 3];
        }
        sc[0][row] = a0 * 0.125f;
        sc[1][row] = a1 * 0.125f;
    }
    __syncthreads();
    // softmax per head
    for (int h = 0; h < 2; ++h) {
        float lm = -3.4e38f;
        for (int i = t; i < 1024; i += 256) lm = fmaxf(lm, sc[h][i]);
        for (int off = 1; off < 64; off <<= 1) lm = fmaxf(lm, __shfl_xor(lm, off, 64));
        if ((t & 63) == 0) red[t >> 6] = lm;
        __syncthreads();
        float m = fmaxf(fmaxf(red[0], red[1]), fmaxf(red[2], red[3]));
        float ls = 0.f;
        for (int i = t; i < 1024; i += 256) {
            float e = __expf(sc[h][i] - m);
            sc[h][i] = e;
            ls += e;
        }
        for (int off = 1; off < 64; off <<= 1) ls += __shfl_xor(ls, off, 64);
        if ((t & 63) == 0) red[4 + (t >> 6)] = ls;
        __syncthreads();
        float invL = __builtin_amdgcn_rcpf((red[4] + red[5]) + (red[6] + red[7]));
        for (int i = t; i < 1024; i += 256) sc[h][i] *= invL;
        __syncthreads();
    }
    // hbar[h][c] = sum_t w[h][t] * hs[t][c]   (coalesced over c)
    {
        int h = t >> 7, c0 = t & 127;
        float a0 = 0.f, a1 = 0.f, a2 = 0.f, a3 = 0.f;
        for (int row = 0; row < 1024; row += 4) {
            a0 += sc[h][row]     * hb[(size_t)(row)     * 128 + c0];
            a1 += sc[h][row + 1] * hb[(size_t)(row + 1) * 128 + c0];
            a2 += sc[h][row + 2] * hb[(size_t)(row + 2) * 128 + c0];
            a3 += sc[h][row + 3] * hb[(size_t)(row + 3) * 128 + c0];
        }
        hbarw[h][c0] = (a0 + a1) + (a2 + a3);
    }
    __syncthreads();
    if (t < 128) { // att[64h+d] = bv + hbar[h] @ Wv[:,64h+d]
        int h = t >> 6;
        float acc = bv[t];
        for (int c = 0; c < 128; ++c) acc += hbarw[h][c] * Wv[c * 128 + t];
        att[t] = acc;
    }
    __syncthreads();
    if (t < 128) {
        float acc = bo[t];
        for (int c = 0; c < 128; ++c) acc += att[c] * Wo[c * 128 + t];
        yv[t] = acc;
    }
    __syncthreads();
    if (t < 18) {
        float acc = bfc[t];
        for (int c = 0; c < 128; ++c) acc += yv[c] * Wfc[c * 18 + t];
        out[b * 18 + t] = acc;
    }
}

extern "C" void kernel_launch(void* const* d_in, const int* in_sizes, int n_in,
                              void* d_out, int out_size, void* d_ws, size_t ws_size,
                              hipStream_t stream) {
    const float* x    = (const float*)d_in[0];
    const float* w1d  = (const float*)d_in[1];
    const float* b1d  = (const float*)d_in[2];
    const float* w1p  = (const float*)d_in[3];
    const float* b1p  = (const float*)d_in[4];
    const float* w2d  = (const float*)d_in[5];
    const float* b2d  = (const float*)d_in[6];
    const float* w2p  = (const float*)d_in[7];
    const float* b2p  = (const float*)d_in[8];
    const float* w3d  = (const float*)d_in[9];
    const float* b3d  = (const float*)d_in[10];
    const float* w3p  = (const float*)d_in[11];
    const float* b3p  = (const float*)d_in[12];
    const float* Ui   = (const float*)d_in[13];
    const float* Vi   = (const float*)d_in[14];
    const float* Uh   = (const float*)d_in[15];
    const float* Vh   = (const float*)d_in[16];
    const float* bi   = (const float*)d_in[17];
    const float* bh   = (const float*)d_in[18];
    const float* Wq   = (const float*)d_in[19];
    const float* bq   = (const float*)d_in[20];
    const float* Wk   = (const float*)d_in[21];
    // d_in[22] = bk: provably cancels in softmax (constant shift per (b,h))
    const float* Wv   = (const float*)d_in[23];
    const float* bv   = (const float*)d_in[24];
    const float* Wo   = (const float*)d_in[25];
    const float* bo   = (const float*)d_in[26];
    const float* Wfc  = (const float*)d_in[27];
    const float* bfc  = (const float*)d_in[28];

    float* ri = (float*)d_ws;                       // B*S*16 floats (2 MB)
    float* hs = ri + (size_t)BB * SS * 16;          // B*S*128 floats (16 MB)

    conv_ri_kernel<<<dim3(512), dim3(256), 0, stream>>>(
        x, w1d, b1d, w1p, b1p, w2d, b2d, w2p, b2p, w3d, b3d, w3p, b3p, Ui, ri);
    lstm_scan_kernel<<<dim3(32), dim3(128), 73856, stream>>>(
        ri, Uh, Vi, Vh, bi, bh, hs);
    attn_head_kernel<<<dim3(32), dim3(256), 0, stream>>>(
        hs, Wq, bq, Wk, Wv, bv, Wo, bo, Wfc, bfc, (float*)d_out);
}